// Round 1
// baseline (168.825 us; speedup 1.0000x reference)
//
#include <hip/hip_runtime.h>

typedef unsigned short u16;
typedef unsigned int u32;
typedef short bf16x8 __attribute__((ext_vector_type(8)));
typedef float f32x4 __attribute__((ext_vector_type(4)));

#define HH 128

__device__ __forceinline__ u16 f2bf(float f) {
  u32 u = __float_as_uint(f);
  u += 0x7fffu + ((u >> 16) & 1u);  // round-to-nearest-even
  return (u16)(u >> 16);
}
__device__ __forceinline__ u32 pack2(float a, float b) {
  return (u32)f2bf(a) | ((u32)f2bf(b) << 16);
}

__device__ __forceinline__ void lds_dma16(const void* g, void* l) {
  __builtin_amdgcn_global_load_lds(
      (const __attribute__((address_space(1))) u32*)g,
      (__attribute__((address_space(3))) u32*)l, 16, 0, 0);
}

// ---------------------------------------------------------------------------
// Pre-pass: fused W_comb (bf16), chunk-transposed + bank-swizzled, into d_ws.
// Layout: 16B chunk index (((q*16+kc)*512+n)*4+p) == tid holds
//   W[k = kc*32 + lq*8 + j][col n],  lq = p ^ (n&3) ^ ((n>>2)&3)
// Fused: k<384 -> W_cat[k][q*512+n];  k>=384 -> (n<128 ? 0 : W_exp[k-384][q*384+n-128])
// ---------------------------------------------------------------------------
__global__ void prep_w(const float* __restrict__ Wcat,
                       const float* __restrict__ Wexp, u16* __restrict__ Wc) {
  int tid = blockIdx.x * 256 + threadIdx.x;  // 0 .. 131071
  int p = tid & 3;
  int n = (tid >> 2) & 511;
  int kc = (tid >> 11) & 15;
  int q = tid >> 15;
  int lq = p ^ (n & 3) ^ ((n >> 2) & 3);
  int k0 = kc * 32 + lq * 8;
  float v[8];
#pragma unroll
  for (int j = 0; j < 8; ++j) {
    int k = k0 + j;
    v[j] = (k < 384) ? Wcat[k * 2048 + q * 512 + n]
                     : ((n < 128) ? 0.f : Wexp[(k - 384) * 1536 + q * 384 + (n - 128)]);
  }
  uint4 pk;
  pk.x = pack2(v[0], v[1]);
  pk.y = pack2(v[2], v[3]);
  pk.z = pack2(v[4], v[5]);
  pk.w = pack2(v[6], v[7]);
  ((uint4*)Wc)[tid] = pk;
}

// ---------------------------------------------------------------------------
// Fused GEMM + gate epilogue.
// Block: one (b,q) group x 64-row tile. 4 waves; wave w owns all 64 rows and
// columns {g*128 + w*32 + u*16 + c} for g in 0..3 (the softmax-coupled set).
// ---------------------------------------------------------------------------
__global__ __launch_bounds__(256, 2) void fused_gate(
    const float* __restrict__ CNN, const float* __restrict__ gaz,
    const float* __restrict__ gazb, const float* __restrict__ gm,
    const float* __restrict__ exper, const u16* __restrict__ Wc,
    const float* __restrict__ bcat, const float* __restrict__ bexp,
    float* __restrict__ out) {
  __shared__ u16 Abuf[64 * 32];    // 4 KB
  __shared__ u16 Wbuf[512 * 32];   // 32 KB, layout [n][k-in-chunk] swizzled

  const int tid = threadIdx.x;
  const int bx = blockIdx.x;
  const int tile = bx & 7;
  const int grp = bx >> 3;
  const int b = grp >> 2;
  const int q = grp & 3;
  const int s_base = tile * 64;
  const int lane = tid & 63;
  const int wave = tid >> 6;
  const int l15 = lane & 15;
  const int quad = lane >> 4;
  const int physq = quad ^ (lane & 3) ^ ((lane >> 2) & 3);  // XOR bank swizzle

  // A-staging assignment: thread -> (row, phys 16B slot)
  const int arow = tid >> 2;  // 0..63
  const int ap = tid & 3;
  const int alq = ap ^ (arow & 3) ^ ((arow >> 2) & 3);
  const int srow = s_base + arow;
  const float* s0 = CNN + (size_t)(b * 2048 + q * 512 + srow) * HH;
  const float* s1 = ((q & 1) ? gazb : gaz) + (size_t)(b * 512 + srow) * HH;
  const float* s2 = gm + (size_t)(b * 512 + srow) * HH;
  const float* s3 = exper + (size_t)(b * 512 + srow) * HH;

  const u16* wsrc = Wc + (size_t)q * 16 * 512 * 32;

  f32x4 acc[4][4][2];  // [row-tile][gate-group][16-col half]
#pragma unroll
  for (int rt = 0; rt < 4; ++rt)
#pragma unroll
    for (int gg = 0; gg < 4; ++gg)
#pragma unroll
      for (int u = 0; u < 2; ++u) acc[rt][gg][u] = (f32x4)0.f;

  for (int kc = 0; kc < 16; ++kc) {
    // ---- stage A: gather 8 fp32 from the right source, convert to bf16 ----
    const int k0 = kc * 32 + alq * 8;
    const int sel = k0 >> 7;
    const float* sp = (sel == 0) ? s0 : (sel == 1) ? s1 : (sel == 2) ? s2 : s3;
    sp += (k0 & 127);
    float4 f0 = *(const float4*)sp;
    float4 f1 = *(const float4*)(sp + 4);
    uint4 pk;
    pk.x = pack2(f0.x, f0.y);
    pk.y = pack2(f0.z, f0.w);
    pk.z = pack2(f1.x, f1.y);
    pk.w = pack2(f1.z, f1.w);
    *(uint4*)&Abuf[arow * 32 + ap * 8] = pk;

    // ---- stage W: 8 x 4KB async DMA (width=16) ----
    const u16* wchunk = wsrc + (size_t)kc * 512 * 32;
#pragma unroll
    for (int i = 0; i < 8; ++i)
      lds_dma16(wchunk + i * 2048 + wave * 512 + lane * 8,
                &Wbuf[i * 2048 + wave * 512]);
    __syncthreads();

    // ---- fragments + MFMA ----
    bf16x8 af[4];
#pragma unroll
    for (int rt = 0; rt < 4; ++rt)
      af[rt] = *(const bf16x8*)&Abuf[(rt * 16 + l15) * 32 + physq * 8];
    bf16x8 bfr[4][2];
#pragma unroll
    for (int gg = 0; gg < 4; ++gg)
#pragma unroll
      for (int u = 0; u < 2; ++u) {
        const int n = gg * 128 + wave * 32 + u * 16 + l15;
        bfr[gg][u] = *(const bf16x8*)&Wbuf[n * 32 + physq * 8];
      }
#pragma unroll
    for (int rt = 0; rt < 4; ++rt)
#pragma unroll
      for (int gg = 0; gg < 4; ++gg)
#pragma unroll
        for (int u = 0; u < 2; ++u)
          acc[rt][gg][u] = __builtin_amdgcn_mfma_f32_16x16x32_bf16(
              af[rt], bfr[gg][u], acc[rt][gg][u], 0, 0, 0);
    __syncthreads();
  }

  // ---- epilogue: tanh / sigmoid / softmax-of-3 / weighted state sum ----
  const float* bcq = bcat + q * 512;
  const float* beq = bexp + q * 384;
  const size_t cnnbase = (size_t)(b * 2048 + q * 512 + s_base) * HH;
  const size_t expbase = (size_t)(b * 512 + s_base) * HH;
  const size_t outbase = (size_t)((q * 32 + b) * 512 + s_base) * HH;
#pragma unroll
  for (int u = 0; u < 2; ++u) {
    const int h = wave * 32 + u * 16 + l15;
    const float bc0 = bcq[h];
    const float bc1 = bcq[128 + h];
    const float bc2 = bcq[256 + h];
    const float bc3 = bcq[384 + h];
    const float be1 = beq[h];
    const float be2 = beq[128 + h];
    const float be3 = beq[256 + h];
#pragma unroll
    for (int rt = 0; rt < 4; ++rt) {
#pragma unroll
      for (int r = 0; r < 4; ++r) {
        const int row = rt * 16 + quad * 4 + r;
        const float c0 = acc[rt][0][u][r] + bc0;
        const float p1 = acc[rt][1][u][r] + bc1 + be1;
        const float p2 = acc[rt][2][u][r] + bc2 + be2;
        const float p3 = acc[rt][3][u][r] + bc3 + be3;
        const float e2c = __expf(2.f * c0);
        const float ns = 1.f - 2.f * __builtin_amdgcn_rcpf(e2c + 1.f);  // tanh
        const float g1 = __builtin_amdgcn_rcpf(1.f + __expf(-p1));
        const float g2 = __builtin_amdgcn_rcpf(1.f + __expf(-p2));
        const float g3 = __builtin_amdgcn_rcpf(1.f + __expf(-p3));
        const float e1 = __expf(g1);
        const float e2 = __expf(g2);
        const float e3 = __expf(g3);
        const float inv = __builtin_amdgcn_rcpf(e1 + e2 + e3);
        const float cnn = CNN[cnnbase + (size_t)row * HH + h];
        const float ex = exper[expbase + (size_t)row * HH + h];
        out[outbase + (size_t)row * HH + h] = (e1 * ns + e2 * cnn + e3 * ex) * inv;
      }
    }
  }
}

extern "C" void kernel_launch(void* const* d_in, const int* in_sizes, int n_in,
                              void* d_out, int out_size, void* d_ws, size_t ws_size,
                              hipStream_t stream) {
  const float* CNN = (const float*)d_in[0];
  const float* gaz = (const float*)d_in[1];
  const float* gazb = (const float*)d_in[2];
  const float* gm = (const float*)d_in[3];
  const float* exper = (const float*)d_in[4];
  const float* Wcat = (const float*)d_in[5];
  const float* bcat = (const float*)d_in[6];
  const float* Wexp = (const float*)d_in[7];
  const float* bexp = (const float*)d_in[8];
  u16* Wc = (u16*)d_ws;  // 2 MB fused bf16 weights

  prep_w<<<512, 256, 0, stream>>>(Wcat, Wexp, Wc);
  fused_gate<<<1024, 256, 0, stream>>>(CNN, gaz, gazb, gm, exper, Wc, bcat,
                                       bexp, (float*)d_out);
}